// Round 9
// baseline (501.862 us; speedup 1.0000x reference)
//
#include <hip/hip_runtime.h>

// Problem constants (from reference)
constexpr int N_NODES = 100000;
constexpr int N_EDGES = 1600000;
constexpr int D = 64;          // D_IN == D_OUT == 64

// Fine buckets: 64 nodes (one k_bucket block). Coarse buckets: 2048 nodes.
constexpr int BSH    = 6;
constexpr int BN     = 1 << BSH;                              // 64
constexpr int NBUCK  = (N_NODES + BN - 1) / BN;               // 1563
constexpr int CSH    = 11;
constexpr int NC     = (N_NODES + (1 << CSH) - 1) >> CSH;     // 49 coarse buckets
constexpr int NPART  = 200;                                   // partition blocks
constexpr int EPB    = N_EDGES / NPART;                       // 8000 (exact)
constexpr int CAPC   = 35328;  // coarse slab cap (mean 32653, sd 179 -> 15-sigma)
constexpr int CHUNK  = 4096;   // pass-B chunk
constexpr int NCHUNK = (CAPC + CHUNK - 1) / CHUNK;            // 9
constexpr int CAP    = 2048;   // fine-bucket LDS cap (mean 1024, sd 32)
constexpr int NCVT   = (N_NODES * D / 4) / 256;               // 6250 cvt blocks

// ---------------------------------------------------------------------------
// Workspace layout (bytes). Total 40,267,776 <= 40,280,064 (verified avail).
// ---------------------------------------------------------------------------
constexpr size_t OFF_CCUR   = 0;          // NC ints (coarse slab cursors)
constexpr size_t OFF_NCUR   = 1024;       // N_NODES ints (degrees, then rank cursors)
constexpr size_t OFF_NST    = 401408;     // (N_NODES+1) ints (node CSR starts)
constexpr size_t OFF_W16    = 801792;     // 64*128 bf16 = 16 KB
constexpr size_t OFF_EA     = 819200;     // NC*CAPC uint2 = 13,848,576
constexpr size_t OFF_EB     = 14667776;   // N_EDGES uint2 = 12.8 MB (node-sorted CSR)
constexpr size_t OFF_FEAT16 = 27467776;   // N_NODES*64 bf16
constexpr size_t WS_NEEDED  = OFF_FEAT16 + (size_t)N_NODES * D * 2;  // 40,267,776

typedef short  bf16x8 __attribute__((ext_vector_type(8)));
typedef float  f32x4  __attribute__((ext_vector_type(4)));

union FragU { unsigned u[4]; bf16x8 v; };

__device__ __forceinline__ unsigned short f2bf(float f) {   // RNE f32 -> bf16
    unsigned u = __float_as_uint(f);
    u += 0x7fffu + ((u >> 16) & 1u);
    return (unsigned short)(u >> 16);
}

// ---------------------------------------------------------------------------
// K0: zero degree counters and coarse cursors (ws poisoned pre-launch).
// ---------------------------------------------------------------------------
__global__ __launch_bounds__(256) void k_zero(int* __restrict__ ncur,
                                              int* __restrict__ ccur) {
    const int stride = gridDim.x * 256;
    for (int i = blockIdx.x * 256 + threadIdx.x; i < N_NODES; i += stride)
        ncur[i] = 0;
    for (int i = blockIdx.x * 256 + threadIdx.x; i < NC; i += stride)
        ccur[i] = 0;
}

// ---------------------------------------------------------------------------
// K1: blocks [0,NCVT) convert feat f32->bf16; [NCVT,NCVT+NPART) accumulate
// per-node degrees (global atomics, ~16 edges/node = low contention); last
// block builds combined W16[j][k] (k<64 = W_self, k>=64 = W_neigh).
// ---------------------------------------------------------------------------
__global__ __launch_bounds__(256) void k_pre(const float4* __restrict__ feat4,
                                             unsigned short* __restrict__ feat16,
                                             const float* __restrict__ Wn,
                                             const float* __restrict__ Ws,
                                             unsigned short* __restrict__ W16,
                                             const int* __restrict__ dst,
                                             int* __restrict__ ncur) {
    const int b   = blockIdx.x;
    const int tid = threadIdx.x;
    if (b < NCVT) {
        const int i = b * 256 + tid;
        float4 v = feat4[i];
        ushort4 o;
        o.x = f2bf(v.x); o.y = f2bf(v.y); o.z = f2bf(v.z); o.w = f2bf(v.w);
        *(ushort4*)&feat16[(size_t)i * 4] = o;
    } else if (b < NCVT + NPART) {
        const int base = (b - NCVT) * EPB;
        for (int k = tid; k < EPB; k += 256)
            atomicAdd(&ncur[dst[base + k]], 1);
    } else {
        for (int e = tid; e < D * 128; e += 256) {
            const int j = e >> 7, k = e & 127;
            const float w = (k < D) ? Ws[j * D + k] : Wn[j * D + (k - D)];
            W16[e] = f2bf(w);
        }
    }
}

// ---------------------------------------------------------------------------
// K2: partition edges into 49 coarse slabs. Runs of ~163 entries (1.3 KB) ->
// fully coalesced writes (fixes R8's 96 MB write amplification).
// Entry: src(17 bits) | node-within-coarse(11 bits) << 17, weight.
// ---------------------------------------------------------------------------
__global__ __launch_bounds__(256) void k_pA(const int* __restrict__ src,
                                            const int* __restrict__ dst,
                                            const float* __restrict__ ew,
                                            int* __restrict__ ccur,
                                            uint2* __restrict__ ea) {
    __shared__ int l[NC];
    const int tid  = threadIdx.x;
    const int base = blockIdx.x * EPB;
    if (tid < NC) l[tid] = 0;
    __syncthreads();
    for (int k = tid; k < EPB; k += 256)
        atomicAdd(&l[dst[base + k] >> CSH], 1);
    __syncthreads();
    if (tid < NC) {
        const int c = l[tid];
        l[tid] = c ? atomicAdd(&ccur[tid], c) : 0;
    }
    __syncthreads();
    for (int k = tid; k < EPB; k += 256) {
        const int e = base + k;
        const int d = dst[e];
        const int c = d >> CSH;
        const int pos = atomicAdd(&l[c], 1);
        if (pos < CAPC)
            ea[(size_t)c * CAPC + pos] =
                make_uint2((unsigned)src[e] | ((unsigned)(d & ((1 << CSH) - 1)) << 17),
                           __float_as_uint(ew[e]));
    }
}

// ---------------------------------------------------------------------------
// K3: single-block exclusive scan of the 100K node degrees -> nst[] (node CSR
// starts); re-zeroes ncur so k_pB can reuse it as rank counters.
// 5 tiles x 24576 (1024 thr x 24 ints, int4 loads, values kept in registers).
// ---------------------------------------------------------------------------
__global__ __launch_bounds__(1024) void k_scan(int* __restrict__ ncur,
                                               int* __restrict__ nst) {
    __shared__ int s[1024];
    __shared__ int carry_s;
    const int t = threadIdx.x;
    if (t == 0) carry_s = 0;
    __syncthreads();
    for (int tile = 0; tile < 5; ++tile) {
        const int base = tile * 24576 + t * 24;
        int v[24];
        int sum = 0;
#pragma unroll
        for (int i = 0; i < 24; i += 4) {
            int4 q = make_int4(0, 0, 0, 0);
            if (base + i + 3 < N_NODES) {
                q = *(const int4*)&ncur[base + i];
            } else {
                if (base + i     < N_NODES) q.x = ncur[base + i];
                if (base + i + 1 < N_NODES) q.y = ncur[base + i + 1];
                if (base + i + 2 < N_NODES) q.z = ncur[base + i + 2];
                if (base + i + 3 < N_NODES) q.w = ncur[base + i + 3];
            }
            v[i] = q.x; v[i + 1] = q.y; v[i + 2] = q.z; v[i + 3] = q.w;
            sum += q.x + q.y + q.z + q.w;
        }
        s[t] = sum;
        __syncthreads();
        for (int off = 1; off < 1024; off <<= 1) {
            int u = (t >= off) ? s[t - off] : 0;
            __syncthreads();
            s[t] += u;
            __syncthreads();
        }
        int run = carry_s + s[t] - sum;   // carry_s stable (updated behind barrier)
#pragma unroll
        for (int i = 0; i < 24; ++i) {
            const int idx = base + i;
            if (idx < N_NODES) { nst[idx] = run; ncur[idx] = 0; }
            run += v[i];
        }
        __syncthreads();
        if (t == 0) carry_s += s[1023];
        __syncthreads();
    }
    if (t == 0) nst[N_NODES] = carry_s;   // == N_EDGES
}

// ---------------------------------------------------------------------------
// K4: pass B — place each coarse entry directly into its final node-sorted
// CSR slot: r = rank via atomic (ncur reused, zeroed by k_scan), slot =
// nst[node] + r. Writes are 8-B scatters confined to a ~280 KB per-coarse
// window -> absorbed by L2, evicted as full lines. Output entry: {src, w}.
// ---------------------------------------------------------------------------
__global__ __launch_bounds__(256) void k_pB(const uint2* __restrict__ ea,
                                            const int* __restrict__ ccur,
                                            const int* __restrict__ nst,
                                            int* __restrict__ rcur,
                                            uint2* __restrict__ eb) {
    const int c = blockIdx.x / NCHUNK;
    const int k = blockIdx.x % NCHUNK;
    int cnt = ccur[c];
    if (cnt > CAPC) cnt = CAPC;
    const int start = k * CHUNK;
    int end = start + CHUNK;
    if (end > cnt) end = cnt;
    const uint2* slab = ea + (size_t)c * CAPC;
    const int nbase = c << CSH;
    for (int i = start + threadIdx.x; i < end; i += 256) {
        const uint2 e = slab[i];
        const int node = nbase + (int)(e.x >> 17);
        const int r = atomicAdd(&rcur[node], 1);
        eb[nst[node] + r] = make_uint2(e.x & 0x1FFFF, e.y);
    }
}

// ---------------------------------------------------------------------------
// K5: gather + MFMA finalize. Entries arrive node-sorted; per-node starts and
// degrees come straight from nst (no histogram, no sort, no LDS atomics).
//  P1: coalesced stage of the bucket's CSR segment into LDS
//  P2: R5/R7/R8-verified aggregate (4 groups of 16 lanes, stride 4)
//  P3: R5/R7/R8-verified MFMA epilogue (agg frags via uint2 LDS loads)
// ---------------------------------------------------------------------------
__global__ __launch_bounds__(256) void k_bucket(const uint2* __restrict__ feat16u2,
                                                const unsigned short* __restrict__ feat16,
                                                const int* __restrict__ nst,
                                                const uint2* __restrict__ eb,
                                                const unsigned short* __restrict__ W16,
                                                const float* __restrict__ bias,
                                                float* __restrict__ out) {
    __shared__ uint2 ent[CAP];                        // 16 KB, node-sorted
    __shared__ __align__(16) uint2 aggrow[BN * 16];   // 8 KB (64 rows x 128 B bf16)
    __shared__ int hh[BN], st[BN];
    const int tid = threadIdx.x;
    const int b   = blockIdx.x;
    const int node0b = b * BN;
    const int s0 = nst[node0b];
    int s1idx = node0b + BN;
    if (s1idx > N_NODES) s1idx = N_NODES;
    const int s1 = nst[s1idx];
    int cnt = s1 - s0;
    if (cnt > CAP) cnt = CAP;

    if (tid < BN) {
        const int idx = node0b + tid;
        if (idx < N_NODES) {
            st[tid] = nst[idx] - s0;
            hh[tid] = nst[idx + 1] - nst[idx];
        } else {
            st[tid] = 0;
            hh[tid] = 0;
        }
    }
    for (int i = tid; i < cnt; i += 256) ent[i] = eb[s0 + i];
    __syncthreads();

    // P2: aggregate — verified structure
    const int wave = tid >> 6, lane = tid & 63;
    const int group = lane >> 4, gl = lane & 15;
    for (int t = 0; t < 16; ++t) {
        const int dl  = wave * 16 + t;
        const int ss  = st[dl];
        const int deg = hh[dl];
        const int se  = ss + deg;
        float4 acc = make_float4(0.f, 0.f, 0.f, 0.f);
        for (int e = ss + group; e < se; e += 4) {
            const uint2 en = ent[e];
            const float w  = __uint_as_float(en.y);
            const uint2 p  = feat16u2[(size_t)(en.x & 0x1FFFF) * 16 + gl];
            acc.x = fmaf(__uint_as_float(p.x << 16),         w, acc.x);
            acc.y = fmaf(__uint_as_float(p.x & 0xFFFF0000u), w, acc.y);
            acc.z = fmaf(__uint_as_float(p.y << 16),         w, acc.z);
            acc.w = fmaf(__uint_as_float(p.y & 0xFFFF0000u), w, acc.w);
        }
#pragma unroll
        for (int m = 16; m <= 32; m <<= 1) {
            acc.x += __shfl_xor(acc.x, m);
            acc.y += __shfl_xor(acc.y, m);
            acc.z += __shfl_xor(acc.z, m);
            acc.w += __shfl_xor(acc.w, m);
        }
        if (group == 0) {
            const float inv = 1.0f / fmaxf((float)deg, 1.0f);
            uint2 o;
            o.x = (unsigned)f2bf(acc.x * inv) | ((unsigned)f2bf(acc.y * inv) << 16);
            o.y = (unsigned)f2bf(acc.z * inv) | ((unsigned)f2bf(acc.w * inv) << 16);
            aggrow[dl * 16 + gl] = o;
        }
    }
    __syncthreads();

    // P3: MFMA finalize (verified layouts)
    const int quad = lane >> 4, r = lane & 15;
    const int node0 = node0b + wave * 16;
    int arow = node0 + r;
    if (arow > N_NODES - 1) arow = N_NODES - 1;

    bf16x8 a[4], bb[4][4];
    a[0] = *(const bf16x8*)&feat16[(size_t)arow * 64 +      quad * 8];
    a[1] = *(const bf16x8*)&feat16[(size_t)arow * 64 + 32 + quad * 8];
    {
        const int rbase = (wave * 16 + r) * 16;
        FragU f2, f3;
        uint2 lo = aggrow[rbase + 2 * quad];
        uint2 hi = aggrow[rbase + 2 * quad + 1];
        f2.u[0] = lo.x; f2.u[1] = lo.y; f2.u[2] = hi.x; f2.u[3] = hi.y;
        lo = aggrow[rbase + 8 + 2 * quad];
        hi = aggrow[rbase + 8 + 2 * quad + 1];
        f3.u[0] = lo.x; f3.u[1] = lo.y; f3.u[2] = hi.x; f3.u[3] = hi.y;
        a[2] = f2.v;
        a[3] = f3.v;
    }
#pragma unroll
    for (int nt = 0; nt < 4; ++nt)
#pragma unroll
        for (int kc = 0; kc < 4; ++kc)
            bb[nt][kc] = *(const bf16x8*)&W16[(size_t)(nt * 16 + r) * 128 + kc * 32 + quad * 8];

    f32x4 acc[4] = {};
#pragma unroll
    for (int kc = 0; kc < 4; ++kc)
#pragma unroll
        for (int nt = 0; nt < 4; ++nt)
            acc[nt] = __builtin_amdgcn_mfma_f32_16x16x32_bf16(a[kc], bb[nt][kc], acc[nt], 0, 0, 0);

#pragma unroll
    for (int nt = 0; nt < 4; ++nt) {
        const float bv = bias[nt * 16 + r];
#pragma unroll
        for (int reg = 0; reg < 4; ++reg) {
            const int m = node0 + quad * 4 + reg;
            if (m < N_NODES) out[(size_t)m * 64 + nt * 16 + r] = acc[nt][reg] + bv;
        }
    }
}

// ---------------------------------------------------------------------------
// Fallback path (R1): atomic scatter + shuffle finalize, if ws is too small.
// ---------------------------------------------------------------------------
__global__ __launch_bounds__(256) void fb_zero(float4* __restrict__ out4,
                                               float* __restrict__ deg) {
    const int stride = gridDim.x * blockDim.x;
    int i = blockIdx.x * blockDim.x + threadIdx.x;
    const int total4 = (N_NODES * D) / 4;
    for (int idx = i; idx < total4; idx += stride)
        out4[idx] = make_float4(0.f, 0.f, 0.f, 0.f);
    for (int idx = i; idx < N_NODES; idx += stride)
        deg[idx] = 0.f;
}

__global__ __launch_bounds__(256) void fb_scatter(
    const float* __restrict__ feat, const int* __restrict__ src,
    const int* __restrict__ dst, const float* __restrict__ ew,
    float* __restrict__ out, float* __restrict__ deg) {
    const int gid  = blockIdx.x * blockDim.x + threadIdx.x;
    const int e    = gid >> 6;
    const int lane = gid & 63;
    if (e >= N_EDGES) return;
    atomicAdd(&out[(size_t)dst[e] * D + lane], feat[(size_t)src[e] * D + lane] * ew[e]);
    if (lane == 0) atomicAdd(&deg[dst[e]], 1.0f);
}

__global__ __launch_bounds__(256) void fb_finalize(
    const float* __restrict__ feat, const float* __restrict__ Wn,
    const float* __restrict__ Ws, const float* __restrict__ bias,
    const float* __restrict__ deg, float* __restrict__ out) {
    __shared__ float lWn[D * 65];
    __shared__ float lWs[D * 65];
    for (int idx = threadIdx.x; idx < D * D; idx += 256) {
        const int r = idx >> 6, c = idx & 63;
        lWn[r * 65 + c] = Wn[idx];
        lWs[r * 65 + c] = Ws[idx];
    }
    __syncthreads();
    const int wave = threadIdx.x >> 6;
    const int lane = threadIdx.x & 63;
    const int n = blockIdx.x * 4 + wave;
    if (n >= N_NODES) return;
    const float f  = feat[(size_t)n * D + lane];
    const float sv = out[(size_t)n * D + lane];
    const float inv = 1.0f / fmaxf(deg[n], 1.0f);
    float acc_s = 0.f, acc_n = 0.f;
#pragma unroll
    for (int k = 0; k < D; ++k) {
        acc_s += __shfl(f, k)  * lWs[lane * 65 + k];
        acc_n += __shfl(sv, k) * lWn[lane * 65 + k];
    }
    out[(size_t)n * D + lane] = acc_s + acc_n * inv + bias[lane];
}

// ---------------------------------------------------------------------------
extern "C" void kernel_launch(void* const* d_in, const int* in_sizes, int n_in,
                              void* d_out, int out_size, void* d_ws, size_t ws_size,
                              hipStream_t stream) {
    const float* feat = (const float*)d_in[0];
    const int*   src  = (const int*)  d_in[1];
    const int*   dst  = (const int*)  d_in[2];
    const float* ew   = (const float*)d_in[3];
    const float* Wn   = (const float*)d_in[4];
    const float* Ws   = (const float*)d_in[5];
    const float* bias = (const float*)d_in[6];
    float* out = (float*)d_out;
    char* ws = (char*)d_ws;

    if (ws_size >= WS_NEEDED) {
        int*   ccur = (int*)(ws + OFF_CCUR);
        int*   ncur = (int*)(ws + OFF_NCUR);
        int*   nst  = (int*)(ws + OFF_NST);
        uint2* ea   = (uint2*)(ws + OFF_EA);
        uint2* eb   = (uint2*)(ws + OFF_EB);
        unsigned short* W16    = (unsigned short*)(ws + OFF_W16);
        unsigned short* feat16 = (unsigned short*)(ws + OFF_FEAT16);

        k_zero  <<<128, 256, 0, stream>>>(ncur, ccur);
        k_pre   <<<NCVT + NPART + 1, 256, 0, stream>>>((const float4*)feat, feat16,
                                                       Wn, Ws, W16, dst, ncur);
        k_pA    <<<NPART, 256, 0, stream>>>(src, dst, ew, ccur, ea);
        k_scan  <<<1, 1024, 0, stream>>>(ncur, nst);
        k_pB    <<<NC * NCHUNK, 256, 0, stream>>>(ea, ccur, nst, ncur, eb);
        k_bucket<<<NBUCK, 256, 0, stream>>>((const uint2*)feat16, feat16, nst, eb,
                                            W16, bias, out);
    } else {
        float* deg = (float*)d_ws;
        fb_zero<<<2048, 256, 0, stream>>>((float4*)out, deg);
        fb_scatter<<<(N_EDGES * 64) / 256, 256, 0, stream>>>(feat, src, dst, ew, out, deg);
        fb_finalize<<<(N_NODES + 3) / 4, 256, 0, stream>>>(feat, Wn, Ws, bias, deg, out);
    }
}